// Round 14
// baseline (87.151 us; speedup 1.0000x reference)
//
#include <hip/hip_runtime.h>
#include <hip/hip_bf16.h>
#include <hip/hip_cooperative_groups.h>

namespace cg = cooperative_groups;

#define BSZ 4096
#define DIM 512
#define NCLS 64
#define MARGIN_F 1.0f
#define NT 32                      // 128-tiles per dim
#define NPAIR (NT * (NT + 1) / 2)  // 528 upper-tri pair tiles (by <= bx)
#define NBLK (NPAIR * 2)           // 1056 blocks: 64x128 halves
#define NSL (2 * NT)               // 64-column slices
#define NFIN 16                    // finalize shards (16*256 = 4096 rows)
#define BK 64                      // k-bytes (=elems) per LDS stage, fp8
#define NKS (DIM / BK)             // 8 stages

typedef float floatx4 __attribute__((ext_vector_type(4)));
typedef unsigned char u8;

// ---------------- workspace layout ----------------
#define OFF_PP  (BSZ * DIM)
#define OFF_PN  (OFF_PP + NSL * BSZ * 4)
#define OFF_ACC (OFF_PN + NSL * BSZ * 4)

__device__ __forceinline__ void gld_lds16(const u8* g, u8* l) {
    __builtin_amdgcn_global_load_lds(
        (const __attribute__((address_space(1))) unsigned int*)g,
        (__attribute__((address_space(3))) unsigned int*)l, 16, 0, 0);
}

// ---------- shared device bodies ----------
__device__ __forceinline__ void normalize_body(
        const float* __restrict__ emb, u8* __restrict__ ebf, int blk,
        float* acc_total, int* acc_nv, int* counter2) {
    const int t = threadIdx.x;
    const int lane = t & 63;
    const int row = blk * 4 + (t >> 6);
    const float4* r4 = (const float4*)(emb + (size_t)row * DIM);
    float4 v0 = r4[lane * 2];
    float4 v1 = r4[lane * 2 + 1];
    float s = v0.x * v0.x + v0.y * v0.y + v0.z * v0.z + v0.w * v0.w
            + v1.x * v1.x + v1.y * v1.y + v1.z * v1.z + v1.w * v1.w;
#pragma unroll
    for (int off = 1; off < 64; off <<= 1) s += __shfl_xor(s, off);
    const float inv = 1.0f / fmaxf(sqrtf(s), 1e-12f);

    int d0 = 0, d1 = 0;
    d0 = __builtin_amdgcn_cvt_pk_fp8_f32(v0.x * inv, v0.y * inv, d0, 0);
    d0 = __builtin_amdgcn_cvt_pk_fp8_f32(v0.z * inv, v0.w * inv, d0, 1);
    d1 = __builtin_amdgcn_cvt_pk_fp8_f32(v1.x * inv, v1.y * inv, d1, 0);
    d1 = __builtin_amdgcn_cvt_pk_fp8_f32(v1.z * inv, v1.w * inv, d1, 1);
    uint2 o; o.x = (unsigned)d0; o.y = (unsigned)d1;
    ((uint2*)(ebf + (size_t)row * DIM))[lane] = o;

    if (blk == 0 && t == 0) { *acc_total = 0.0f; *acc_nv = 0; *counter2 = 0; }
}

// gemm body: R12's proven 64x128 fp8 tile k-loop + one-writer epilogue.
// LDS buffers passed in so the fused kernel can reuse one allocation.
__device__ __forceinline__ void gemm_body(
        const u8* __restrict__ ebf, const int* __restrict__ labels,
        float* __restrict__ part_ps, unsigned* __restrict__ part_nm, int blk,
        u8 (*sA)[64 * BK], u8 (*sB)[128 * BK],
        int* sLI, int* sLJ, float* sCPps, float* sCPnm) {
    const int p = blk >> 1;
    const int h2 = blk & 1;
    int rem = p, by = 0;
    while (rem >= NT - by) { rem -= NT - by; ++by; }
    const int bx = by + rem;
    const bool offd = (bx != by);

    const int t = threadIdx.x;
    const int row0 = by * 128 + h2 * 64;
    const int col0 = bx * 128;

    if (t < 64) sLI[t] = labels[row0 + t];
    else if (t < 192) sLJ[t - 64] = labels[col0 + (t - 64)];

    const int lane = t & 63;
    const int wave = t >> 6;
    const int wr = (wave >> 1) * 32;
    const int wc = (wave & 1) * 64;
    const int l15 = lane & 15;
    const int quad = lane >> 4;

    const int sa = t;
    const int ga = (sa & 3) ^ ((sa >> 3) & 3);
    const u8* gA0 = ebf + (size_t)(row0 + (sa >> 2)) * DIM + ga * 16;
    const int sb0 = t, sb1 = 256 + t;
    const int gb0 = (sb0 & 3) ^ ((sb0 >> 3) & 3);
    const int gb1 = (sb1 & 3) ^ ((sb1 >> 3) & 3);
    const u8* gB0 = ebf + (size_t)(col0 + (sb0 >> 2)) * DIM + gb0 * 16;
    const u8* gB1 = ebf + (size_t)(col0 + (sb1 >> 2)) * DIM + gb1 * 16;
    const int lbA = wave * 64 * 16;
    const int lbB0 = wave * 64 * 16;
    const int lbB1 = (256 + wave * 64) * 16;

    floatx4 acc[2][4] = {};

    __syncthreads();                        // sLI/sLJ + LDS reuse safe
    gld_lds16(gA0, &sA[0][lbA]);
    gld_lds16(gB0, &sB[0][lbB0]);
    gld_lds16(gB1, &sB[0][lbB1]);

    int cur = 0;
    for (int ks = 0; ks < NKS; ++ks) {
        __syncthreads();  // vmcnt drained: buf[cur] ready; buf[cur^1] reads done
        if (ks + 1 < NKS) {
            const int kb = (ks + 1) * BK;
            gld_lds16(gA0 + kb, &sA[cur ^ 1][lbA]);
            gld_lds16(gB0 + kb, &sB[cur ^ 1][lbB0]);
            gld_lds16(gB1 + kb, &sB[cur ^ 1][lbB1]);
        }
#pragma unroll
        for (int h = 0; h < 2; ++h) {
            const int co = (((h * 2 + (quad >> 1)) ^ ((l15 >> 1) & 3)) * 16)
                         + (quad & 1) * 8;
            long af[2]; long bf[4];
#pragma unroll
            for (int mi = 0; mi < 2; ++mi)
                af[mi] = *(const long*)(&sA[cur][(wr + mi * 16 + l15) * BK + co]);
#pragma unroll
            for (int ni = 0; ni < 4; ++ni)
                bf[ni] = *(const long*)(&sB[cur][(wc + ni * 16 + l15) * BK + co]);
#pragma unroll
            for (int mi = 0; mi < 2; ++mi)
#pragma unroll
                for (int ni = 0; ni < 4; ++ni)
                    acc[mi][ni] = __builtin_amdgcn_mfma_f32_16x16x32_fp8_fp8(
                        af[mi], bf[ni], acc[mi][ni], 0, 0, 0);
        }
        cur ^= 1;
    }

    const float INF = __uint_as_float(0x7F800000u);
    const int rslice = 2 * bx + (wc >> 6);
    float psc[4] = {0.f, 0.f, 0.f, 0.f};
    float nmc[4] = {INF, INF, INF, INF};
#pragma unroll
    for (int mi = 0; mi < 2; ++mi) {
        const int rbase = wr + mi * 16 + quad * 4;
#pragma unroll
        for (int r = 0; r < 4; ++r) {
            const int rloc = rbase + r;
            const int gi = row0 + rloc;
            const int rl = sLI[rloc];
            float ps = 0.0f, nm = INF;
#pragma unroll
            for (int ni = 0; ni < 4; ++ni) {
                const int cloc = wc + ni * 16 + l15;
                const int gj = col0 + cloc;
                const int cl = sLJ[cloc];
                const float d = __builtin_amdgcn_sqrtf(
                    fmaxf(2.0f - 2.0f * acc[mi][ni][r], 0.0f));
                if (rl == cl) {
                    if (gi != gj) ps += d;
                    if (offd) psc[ni] += d;
                } else {
                    nm = fminf(nm, d);
                    if (offd) nmc[ni] = fminf(nmc[ni], d);
                }
            }
#pragma unroll
            for (int off = 1; off < 16; off <<= 1) {
                ps += __shfl_xor(ps, off);
                nm = fminf(nm, __shfl_xor(nm, off));
            }
            if (l15 == 0) {
                part_ps[rslice * BSZ + gi] = ps;
                part_nm[rslice * BSZ + gi] = __float_as_uint(nm);
            }
        }
    }
    if (offd) {
        const int cslice = 2 * by + h2;
        float cps[4], cnm[4];
#pragma unroll
        for (int ni = 0; ni < 4; ++ni) {
            float ps = psc[ni], nm = nmc[ni];
            ps += __shfl_xor(ps, 16); ps += __shfl_xor(ps, 32);
            nm = fminf(nm, __shfl_xor(nm, 16));
            nm = fminf(nm, __shfl_xor(nm, 32));
            cps[ni] = ps; cnm[ni] = nm;
        }
        if (wave >= 2 && quad == 0) {
#pragma unroll
            for (int ni = 0; ni < 4; ++ni) {
                const int cl = wc + ni * 16 + l15;
                sCPps[cl] = cps[ni];
                sCPnm[cl] = cnm[ni];
            }
        }
        __syncthreads();
        if (wave < 2 && quad == 0) {
#pragma unroll
            for (int ni = 0; ni < 4; ++ni) {
                const int cl = wc + ni * 16 + l15;
                const int gj = col0 + cl;
                const float ps = cps[ni] + sCPps[cl];
                const float nm = fminf(cnm[ni], sCPnm[cl]);
                part_ps[cslice * BSZ + gj] = ps;
                part_nm[cslice * BSZ + gj] = __float_as_uint(nm);
            }
        }
    }
}

__device__ __forceinline__ void finalize_body(
        const float* __restrict__ part_ps, const unsigned* __restrict__ part_nm,
        const int* __restrict__ labels, float* acc_total, int* acc_nv,
        int* counter2, float* out, int blk, int* hist, float* sT, int* sN) {
    const int t = threadIdx.x;
    if (t < NCLS) hist[t] = 0;
    __syncthreads();
    for (int i = t; i < BSZ; i += 256) atomicAdd(&hist[labels[i]], 1);
    __syncthreads();

    const int j = blk * 256 + t;
    float ps = 0.0f;
    float nm = __uint_as_float(0x7F800000u);
#pragma unroll 8
    for (int s = 0; s < NSL; ++s) {
        ps += part_ps[s * BSZ + j];
        nm = fminf(nm, __uint_as_float(part_nm[s * BSZ + j]));
    }
    const int cnt = hist[labels[j]];
    const int pc = cnt - 1;
    const int nc = BSZ - cnt;
    float loss = 0.0f;
    int lv = 0;
    if (pc > 0 && nc > 0) {
        loss = fmaxf(ps / (float)pc - nm + MARGIN_F, 0.0f);
        lv = 1;
    }
#pragma unroll
    for (int off = 1; off < 64; off <<= 1) {
        loss += __shfl_xor(loss, off);
        lv += __shfl_xor(lv, off);
    }
    if ((t & 63) == 0) { sT[t >> 6] = loss; sN[t >> 6] = lv; }
    __syncthreads();
    if (t == 0) {
        const float tt = sT[0] + sT[1] + sT[2] + sT[3];
        const int nn = sN[0] + sN[1] + sN[2] + sN[3];
        __hip_atomic_fetch_add(acc_total, tt, __ATOMIC_ACQ_REL,
                               __HIP_MEMORY_SCOPE_AGENT);
        __hip_atomic_fetch_add(acc_nv, nn, __ATOMIC_ACQ_REL,
                               __HIP_MEMORY_SCOPE_AGENT);
        const int old2 = __hip_atomic_fetch_add(counter2, 1, __ATOMIC_ACQ_REL,
                                                __HIP_MEMORY_SCOPE_AGENT);
        if (old2 == NFIN - 1) {
            const float ft = __hip_atomic_load(acc_total, __ATOMIC_ACQUIRE,
                                               __HIP_MEMORY_SCOPE_AGENT);
            const int fn = __hip_atomic_load(acc_nv, __ATOMIC_ACQUIRE,
                                             __HIP_MEMORY_SCOPE_AGENT);
            out[0] = (fn > 0) ? ft / (float)fn : 0.0f;
        }
    }
}

// ---------------- fused cooperative kernel ----------------
// __launch_bounds__(256,5): VGPR <= ~102 -> 5 blocks/CU -> capacity 1280 >=
// 1056 (R13 failed with no bound: >102 VGPR -> capacity 1024 < 1056).
__global__ __launch_bounds__(256, 5) void ht_fused(
        const float* __restrict__ emb, const int* __restrict__ labels,
        u8* __restrict__ ebf,
        float* __restrict__ part_ps, unsigned* __restrict__ part_nm,
        float* __restrict__ acc_total, int* __restrict__ acc_nv,
        int* __restrict__ counter2, float* __restrict__ out) {
    __shared__ u8 sA[2][64 * BK];
    __shared__ u8 sB[2][128 * BK];
    __shared__ int sLI[128];
    __shared__ int sLJ[128];
    __shared__ float sCPps[128];
    __shared__ float sCPnm[128];
    __shared__ float sT[4];
    __shared__ int sN[4];

    if (blockIdx.x < BSZ / 4)
        normalize_body(emb, ebf, blockIdx.x, acc_total, acc_nv, counter2);

    cg::this_grid().sync();

    gemm_body(ebf, labels, part_ps, part_nm, blockIdx.x,
              sA, sB, sLI, sLJ, sCPps, sCPnm);

    cg::this_grid().sync();

    if (blockIdx.x < NFIN)
        finalize_body(part_ps, part_nm, labels, acc_total, acc_nv, counter2,
                      out, blockIdx.x, sLI, sT, sN);
}

// ---------------- fallback (R12-proven) kernels ----------------
__global__ __launch_bounds__(256) void ht_normalize(
        const float* __restrict__ emb, u8* __restrict__ ebf,
        float* __restrict__ acc_total, int* __restrict__ acc_nv,
        int* __restrict__ counter2) {
    normalize_body(emb, ebf, blockIdx.x, acc_total, acc_nv, counter2);
}

__global__ __launch_bounds__(256) void ht_gemm_reduce(
        const u8* __restrict__ ebf, const int* __restrict__ labels,
        float* __restrict__ part_ps, unsigned* __restrict__ part_nm) {
    __shared__ u8 sA[2][64 * BK];
    __shared__ u8 sB[2][128 * BK];
    __shared__ int sLI[128];
    __shared__ int sLJ[128];
    __shared__ float sCPps[128];
    __shared__ float sCPnm[128];
    gemm_body(ebf, labels, part_ps, part_nm, blockIdx.x,
              sA, sB, sLI, sLJ, sCPps, sCPnm);
}

__global__ __launch_bounds__(256) void ht_finalize(
        const float* __restrict__ part_ps, const unsigned* __restrict__ part_nm,
        const int* __restrict__ labels, float* __restrict__ acc_total,
        int* __restrict__ acc_nv, int* __restrict__ counter2,
        float* __restrict__ out) {
    __shared__ int hist[NCLS];
    __shared__ float sT[4];
    __shared__ int sN[4];
    finalize_body(part_ps, part_nm, labels, acc_total, acc_nv, counter2,
                  out, blockIdx.x, hist, sT, sN);
}

extern "C" void kernel_launch(void* const* d_in, const int* in_sizes, int n_in,
                              void* d_out, int out_size, void* d_ws, size_t ws_size,
                              hipStream_t stream) {
    const float* emb = (const float*)d_in[0];
    const int* labels = (const int*)d_in[1];
    float* out = (float*)d_out;
    char* ws = (char*)d_ws;

    u8* ebf = (u8*)ws;
    float* part_ps = (float*)(ws + OFF_PP);
    unsigned* part_nm = (unsigned*)(ws + OFF_PN);
    float* acc_total = (float*)(ws + OFF_ACC);
    int* acc_nv = (int*)(ws + OFF_ACC + 4);
    int* counter2 = (int*)(ws + OFF_ACC + 8);

    // capture-safe deterministic gate: cooperative only if the whole grid
    // is co-resident (R13 failed here: no launch bound -> capacity 1024 < 1056)
    int maxb = 0;
    hipError_t qerr = hipOccupancyMaxActiveBlocksPerMultiprocessor(
        &maxb, (const void*)ht_fused, 256, 0);
    const bool coop_ok = (qerr == hipSuccess) && (maxb * 256 >= NBLK);

    if (coop_ok) {
        void* args[] = {
            (void*)&emb, (void*)&labels, (void*)&ebf,
            (void*)&part_ps, (void*)&part_nm,
            (void*)&acc_total, (void*)&acc_nv, (void*)&counter2, (void*)&out,
        };
        hipLaunchCooperativeKernel((const void*)ht_fused, dim3(NBLK), dim3(256),
                                   args, 0, stream);
    } else {
        ht_normalize<<<BSZ / 4, 256, 0, stream>>>(emb, ebf, acc_total, acc_nv,
                                                  counter2);
        ht_gemm_reduce<<<NBLK, 256, 0, stream>>>(ebf, labels, part_ps, part_nm);
        ht_finalize<<<NFIN, 256, 0, stream>>>(part_ps, part_nm, labels,
                                              acc_total, acc_nv, counter2, out);
    }
}